// Round 1
// baseline (377.241 us; speedup 1.0000x reference)
//
#include <hip/hip_runtime.h>
#include <hip/hip_bf16.h>
#include <stdint.h>
#include <math.h>

#define S_ 2048
#define H_ 16
#define B_ 2

typedef __attribute__((ext_vector_type(4))) float f32x4;
typedef __attribute__((ext_vector_type(8))) short s16x8;

static __device__ __forceinline__ uint16_t f2bf(float f) {
    union { float f; uint32_t u; } x; x.f = f;
    uint32_t u = x.u;
    return (uint16_t)((u + 0x7FFFu + ((u >> 16) & 1u)) >> 16);
}

static __device__ __forceinline__ void gl_lds16(const uint16_t* g, uint16_t* l) {
    __builtin_amdgcn_global_load_lds(
        (const __attribute__((address_space(1))) unsigned int*)g,
        (__attribute__((address_space(3))) unsigned int*)l, 16, 0, 0);
}

// ---------------- prep kernels ----------------

__global__ void cvt_f32_bf16(const float* __restrict__ in, uint16_t* __restrict__ out, int n4) {
    int i = blockIdx.x * blockDim.x + threadIdx.x;
    if (i >= n4) return;
    float4 v = ((const float4*)in)[i];
    union { uint16_t h[4]; uint64_t q; } pk;
    pk.h[0] = f2bf(v.x); pk.h[1] = f2bf(v.y); pk.h[2] = f2bf(v.z); pk.h[3] = f2bf(v.w);
    ((uint64_t*)out)[i] = pk.q;
}

// in: R x C fp32 row-major  ->  out: C x R bf16 row-major
__global__ void transpose_w(const float* __restrict__ in, uint16_t* __restrict__ out, int R, int C) {
    __shared__ float sm[32][33];
    int r0 = blockIdx.x * 32, c0 = blockIdx.y * 32;
    int t = threadIdx.x;
    int rr = t >> 3, cc = (t & 7) * 4;
    float4 v = *(const float4*)(in + (size_t)(r0 + rr) * C + c0 + cc);
    sm[rr][cc] = v.x; sm[rr][cc + 1] = v.y; sm[rr][cc + 2] = v.z; sm[rr][cc + 3] = v.w;
    __syncthreads();
    union { uint16_t h[4]; uint64_t q; } pk;
    #pragma unroll
    for (int i = 0; i < 4; i++) pk.h[i] = f2bf(sm[cc + i][rr]);
    *(uint64_t*)(out + (size_t)(c0 + rr) * R + r0 + cc) = pk.q;
}

__global__ void rope_table(float* __restrict__ cosT, float* __restrict__ sinT) {
    int i = blockIdx.x * blockDim.x + threadIdx.x; // 2048*32
    int s = i >> 5, j = i & 31;
    float theta = powf(10000.0f, -2.0f * (float)j / 64.0f);
    float ang = (float)s * theta;
    cosT[i] = cosf(ang);
    sinT[i] = sinf(ang);
}

// vb: (bh, s, d=64)  ->  vt: (bh, d=64, s)
__global__ void vtrans(const uint16_t* __restrict__ vb, uint16_t* __restrict__ vt) {
    __shared__ __align__(16) uint16_t sm[64][72];
    int s0 = blockIdx.x * 64;
    int bh = blockIdx.y;
    const uint16_t* src = vb + (size_t)bh * S_ * 64;
    uint16_t* dst = vt + (size_t)bh * 64 * S_;
    int t = threadIdx.x;
    #pragma unroll
    for (int p = 0; p < 2; p++) {
        int off = p * 2048 + t * 8;
        int sl = off >> 6, d = off & 63;
        s16x8 v = *(const s16x8*)(src + (size_t)(s0 + sl) * 64 + d);
        #pragma unroll
        for (int i = 0; i < 8; i++) sm[sl][d + i] = (uint16_t)v[i];
    }
    __syncthreads();
    #pragma unroll
    for (int p = 0; p < 2; p++) {
        int off = p * 2048 + t * 8;
        int d = off >> 6, sl = off & 63;
        union { uint16_t h[8]; s16x8 v; } pk;
        #pragma unroll
        for (int i = 0; i < 8; i++) pk.h[i] = sm[sl + i][d];
        *(s16x8*)(dst + (size_t)d * S_ + s0 + sl) = pk.v;
    }
}

// ---------------- GEMM: C = A(bf16 MxK) @ BT(bf16 NxK)^T + bias ----------------

#define MODE_F32   0
#define MODE_BF16  1
#define MODE_QROPE 2
#define MODE_KV    3

template<int MODE>
__global__ __launch_bounds__(256, 2)
void gemm_bt(const uint16_t* __restrict__ A, const uint16_t* __restrict__ BT,
             const float* __restrict__ bias,
             void* __restrict__ out0, uint16_t* __restrict__ out2,
             const float* __restrict__ cosT, const float* __restrict__ sinT,
             int N, int K)
{
    __shared__ __align__(16) uint16_t smA[128 * 32];
    __shared__ __align__(16) uint16_t smB[128 * 32];
    const int t = threadIdx.x;
    const int l = t & 63;
    const int wid = t >> 6;
    const int wr = wid >> 1, wc = wid & 1;
    const int m0 = blockIdx.x * 128, n0 = blockIdx.y * 128;

    f32x4 acc[4][4];
    #pragma unroll
    for (int i = 0; i < 4; i++)
        #pragma unroll
        for (int j = 0; j < 4; j++) acc[i][j] = (f32x4)(0.0f);

    const int srow = t >> 2;          // (t*8)/32
    const int scol = (t & 3) * 8;     // (t*8)%32
    const uint16_t* aG = A + (size_t)(m0 + srow) * K + scol;
    const uint16_t* bG = BT + (size_t)(n0 + srow) * K + scol;
    uint16_t* lA = smA + t * 8;
    uint16_t* lB = smB + t * 8;

    for (int k0 = 0; k0 < K; k0 += 32) {
        __syncthreads();
        gl_lds16(aG + k0, lA);
        gl_lds16(aG + (size_t)64 * K + k0, lA + 2048);
        gl_lds16(bG + k0, lB);
        gl_lds16(bG + (size_t)64 * K + k0, lB + 2048);
        __syncthreads();
        s16x8 af[4], bfr[4];
        #pragma unroll
        for (int mf = 0; mf < 4; mf++)
            af[mf] = *(const s16x8*)(smA + (wr * 64 + mf * 16 + (l & 15)) * 32 + (l >> 4) * 8);
        #pragma unroll
        for (int nf = 0; nf < 4; nf++)
            bfr[nf] = *(const s16x8*)(smB + (wc * 64 + nf * 16 + (l & 15)) * 32 + (l >> 4) * 8);
        #pragma unroll
        for (int mf = 0; mf < 4; mf++)
            #pragma unroll
            for (int nf = 0; nf < 4; nf++)
                acc[mf][nf] = __builtin_amdgcn_mfma_f32_16x16x32_bf16(af[mf], bfr[nf], acc[mf][nf], 0, 0, 0);
    }

    const int rbase = m0 + wr * 64 + ((l >> 4) << 2);
    const int cbase = n0 + wc * 64 + (l & 15);
    #pragma unroll
    for (int mf = 0; mf < 4; mf++) {
        #pragma unroll
        for (int nf = 0; nf < 4; nf++) {
            const int col = cbase + nf * 16;
            const float bv = bias[col];
            #pragma unroll
            for (int r = 0; r < 4; r++) {
                const int row = rbase + mf * 16 + r;
                float v = acc[mf][nf][r] + bv;
                if constexpr (MODE == MODE_F32) {
                    ((float*)out0)[(size_t)row * N + col] = v;
                } else if constexpr (MODE == MODE_BF16) {
                    ((uint16_t*)out0)[(size_t)row * N + col] = f2bf(v);
                } else {
                    float other = __shfl_xor(v, 1);
                    int s = row & (S_ - 1);
                    int b = row >> 11;
                    if constexpr (MODE == MODE_QROPE) {
                        int h = col >> 6, d = col & 63;
                        float c = cosT[s * 32 + (d >> 1)];
                        float sn = sinT[s * 32 + (d >> 1)];
                        float o = (d & 1) ? (other * sn + v * c) : (v * c - other * sn);
                        ((uint16_t*)out0)[((size_t)(b * H_ + h) * S_ + s) * 64 + d] = f2bf(o);
                    } else { // MODE_KV
                        if (col < 1024) {
                            int h = col >> 6, d = col & 63;
                            float c = cosT[s * 32 + (d >> 1)];
                            float sn = sinT[s * 32 + (d >> 1)];
                            float o = (d & 1) ? (other * sn + v * c) : (v * c - other * sn);
                            ((uint16_t*)out0)[((size_t)(b * H_ + h) * S_ + s) * 64 + d] = f2bf(o);
                        } else {
                            int cc = col - 1024;
                            int h = cc >> 6, d = cc & 63;
                            out2[((size_t)(b * H_ + h) * S_ + s) * 64 + d] = f2bf(v);
                        }
                    }
                }
            }
        }
    }
}

// ---------------- causal flash attention ----------------
// qr,kr: (bh, s, 64) bf16 (rope applied); vt: (bh, 64, s) bf16
// attnf: (b, s, h*64) bf16

__global__ __launch_bounds__(256, 2)
void attn_fa(const uint16_t* __restrict__ qr, const uint16_t* __restrict__ kr,
             const uint16_t* __restrict__ vt, uint16_t* __restrict__ attnf)
{
    __shared__ __align__(16) uint16_t smK[64 * 64];
    __shared__ __align__(16) uint16_t smV[64 * 64];   // V^T: [d][kv]
    __shared__ __align__(16) uint16_t smP[128 * 64];

    const int t = threadIdx.x;
    const int l = t & 63;
    const int w = t >> 6;
    const int q0 = blockIdx.x * 128;
    const int bh = blockIdx.y;
    const uint16_t* qB = qr + (size_t)bh * S_ * 64;
    const uint16_t* kB = kr + (size_t)bh * S_ * 64;
    const uint16_t* vB = vt + (size_t)bh * 64 * S_;

    s16x8 qf[2][2];
    #pragma unroll
    for (int mf = 0; mf < 2; mf++)
        #pragma unroll
        for (int kk = 0; kk < 2; kk++) {
            int row = q0 + w * 32 + mf * 16 + (l & 15);
            int d = kk * 32 + (l >> 4) * 8;
            qf[mf][kk] = *(const s16x8*)(qB + (size_t)row * 64 + d);
        }

    float mrow[2][4], lrow[2][4];
    f32x4 oacc[2][4];
    #pragma unroll
    for (int mf = 0; mf < 2; mf++) {
        #pragma unroll
        for (int r = 0; r < 4; r++) { mrow[mf][r] = -INFINITY; lrow[mf][r] = 0.0f; }
        #pragma unroll
        for (int nf = 0; nf < 4; nf++) oacc[mf][nf] = (f32x4)(0.0f);
    }

    const int nkt = (q0 + 128) >> 6;
    const int vrow = t >> 3;        // (t*8)/64
    const int vcol = (t & 7) * 8;
    for (int kt = 0; kt < nkt; kt++) {
        const int kv0 = kt * 64;
        __syncthreads();
        gl_lds16(kB + (size_t)(kv0 + vrow) * 64 + vcol, smK + t * 8);
        gl_lds16(kB + (size_t)(kv0 + vrow + 32) * 64 + vcol, smK + 2048 + t * 8);
        gl_lds16(vB + (size_t)vrow * S_ + kv0 + vcol, smV + t * 8);
        gl_lds16(vB + (size_t)(vrow + 32) * S_ + kv0 + vcol, smV + 2048 + t * 8);
        __syncthreads();

        f32x4 sacc[2][4];
        #pragma unroll
        for (int mf = 0; mf < 2; mf++)
            #pragma unroll
            for (int nf = 0; nf < 4; nf++) sacc[mf][nf] = (f32x4)(0.0f);
        #pragma unroll
        for (int kk = 0; kk < 2; kk++) {
            #pragma unroll
            for (int nf = 0; nf < 4; nf++) {
                s16x8 kf = *(const s16x8*)(smK + (nf * 16 + (l & 15)) * 64 + kk * 32 + (l >> 4) * 8);
                #pragma unroll
                for (int mf = 0; mf < 2; mf++)
                    sacc[mf][nf] = __builtin_amdgcn_mfma_f32_16x16x32_bf16(qf[mf][kk], kf, sacc[mf][nf], 0, 0, 0);
            }
        }

        // online softmax
        #pragma unroll
        for (int mf = 0; mf < 2; mf++) {
            #pragma unroll
            for (int r = 0; r < 4; r++) {
                const int qrow = q0 + w * 32 + mf * 16 + ((l >> 4) << 2) + r;
                float mx = -INFINITY;
                #pragma unroll
                for (int nf = 0; nf < 4; nf++) {
                    int kvcol = kv0 + nf * 16 + (l & 15);
                    float sv = sacc[mf][nf][r] * 0.125f;
                    sv = (kvcol <= qrow) ? sv : -INFINITY;
                    sacc[mf][nf][r] = sv;
                    mx = fmaxf(mx, sv);
                }
                mx = fmaxf(mx, __shfl_xor(mx, 1));
                mx = fmaxf(mx, __shfl_xor(mx, 2));
                mx = fmaxf(mx, __shfl_xor(mx, 4));
                mx = fmaxf(mx, __shfl_xor(mx, 8));
                float newm = fmaxf(mrow[mf][r], mx);
                float fac = expf(mrow[mf][r] - newm);
                float psum = 0.0f;
                #pragma unroll
                for (int nf = 0; nf < 4; nf++) {
                    float p = expf(sacc[mf][nf][r] - newm);
                    sacc[mf][nf][r] = p;
                    psum += p;
                }
                psum += __shfl_xor(psum, 1);
                psum += __shfl_xor(psum, 2);
                psum += __shfl_xor(psum, 4);
                psum += __shfl_xor(psum, 8);
                lrow[mf][r] = lrow[mf][r] * fac + psum;
                mrow[mf][r] = newm;
                #pragma unroll
                for (int nf = 0; nf < 4; nf++) oacc[mf][nf][r] *= fac;
            }
            #pragma unroll
            for (int nf = 0; nf < 4; nf++)
                #pragma unroll
                for (int r = 0; r < 4; r++)
                    smP[(w * 32 + mf * 16 + ((l >> 4) << 2) + r) * 64 + nf * 16 + (l & 15)] = f2bf(sacc[mf][nf][r]);
        }
        __syncthreads();

        // PV
        #pragma unroll
        for (int kk = 0; kk < 2; kk++) {
            s16x8 pf[2];
            #pragma unroll
            for (int mf = 0; mf < 2; mf++)
                pf[mf] = *(const s16x8*)(smP + (w * 32 + mf * 16 + (l & 15)) * 64 + kk * 32 + (l >> 4) * 8);
            #pragma unroll
            for (int nf = 0; nf < 4; nf++) {
                s16x8 vf = *(const s16x8*)(smV + (nf * 16 + (l & 15)) * 64 + kk * 32 + (l >> 4) * 8);
                #pragma unroll
                for (int mf = 0; mf < 2; mf++)
                    oacc[mf][nf] = __builtin_amdgcn_mfma_f32_16x16x32_bf16(pf[mf], vf, oacc[mf][nf], 0, 0, 0);
            }
        }
    }

    const int b = bh >> 4, h = bh & 15;
    #pragma unroll
    for (int mf = 0; mf < 2; mf++)
        #pragma unroll
        for (int nf = 0; nf < 4; nf++)
            #pragma unroll
            for (int r = 0; r < 4; r++) {
                int qrow = q0 + w * 32 + mf * 16 + ((l >> 4) << 2) + r;
                int d = nf * 16 + (l & 15);
                float o = oacc[mf][nf][r] / lrow[mf][r];
                attnf[((size_t)(b * S_ + qrow)) * 1024 + h * 64 + d] = f2bf(o);
            }
}

// ---------------- launch ----------------

extern "C" void kernel_launch(void* const* d_in, const int* in_sizes, int n_in,
                              void* d_out, int out_size, void* d_ws, size_t ws_size,
                              hipStream_t stream)
{
    const float* x    = (const float*)d_in[0];
    const float* Wq   = (const float*)d_in[1];
    const float* bq   = (const float*)d_in[2];
    const float* Wkv1 = (const float*)d_in[3];
    const float* bkv1 = (const float*)d_in[4];
    const float* Wkv2 = (const float*)d_in[5];
    const float* bkv2 = (const float*)d_in[6];
    const float* Wo   = (const float*)d_in[7];
    const float* bo   = (const float*)d_in[8];
    float* out = (float*)d_out;
    char* ws = (char*)d_ws;

    uint16_t* xb    = (uint16_t*)(ws + 0);            // 4096x1024 bf16   8 MB
    uint16_t* WqT   = (uint16_t*)(ws + 8388608);      // 1024x1024        2 MB
    uint16_t* Wkv1T = (uint16_t*)(ws + 10485760);     // 512x1024         1 MB
    uint16_t* Wkv2T = (uint16_t*)(ws + 11534336);     // 2048x512         2 MB
    uint16_t* WoT   = (uint16_t*)(ws + 13631488);     // 1024x1024        2 MB
    float*    cosT  = (float*)(ws + 15728640);        // 2048x32 f32      256 KB
    float*    sinT  = (float*)(ws + 15990784);        // 256 KB
    uint16_t* qrb   = (uint16_t*)(ws + 16252928);     // (bh,s,d)         8 MB
    uint16_t* kv1b  = (uint16_t*)(ws + 24641536);     // 4096x512         4 MB
    uint16_t* krb   = (uint16_t*)(ws + 28835840);     // (bh,s,d)         8 MB
    uint16_t* vbb   = (uint16_t*)(ws + 37224448);     // (bh,s,d)         8 MB
    uint16_t* vtb   = (uint16_t*)(ws + 45613056);     // (bh,d,s)         8 MB
    uint16_t* attnf = (uint16_t*)(ws + 54001664);     // 4096x1024        8 MB

    cvt_f32_bf16<<<4096, 256, 0, stream>>>(x, xb, 1048576);
    transpose_w<<<dim3(32, 32), 256, 0, stream>>>(Wq, WqT, 1024, 1024);
    transpose_w<<<dim3(32, 16), 256, 0, stream>>>(Wkv1, Wkv1T, 1024, 512);
    transpose_w<<<dim3(16, 64), 256, 0, stream>>>(Wkv2, Wkv2T, 512, 2048);
    transpose_w<<<dim3(32, 32), 256, 0, stream>>>(Wo, WoT, 1024, 1024);
    rope_table<<<256, 256, 0, stream>>>(cosT, sinT);

    // q = x @ Wq + bq, rope -> qrb (bh,s,d)
    gemm_bt<MODE_QROPE><<<dim3(32, 8), 256, 0, stream>>>(xb, WqT, bq, qrb, nullptr, cosT, sinT, 1024, 1024);
    // kv1 = x @ Wkv1 + bkv1 -> bf16 row-major
    gemm_bt<MODE_BF16><<<dim3(32, 4), 256, 0, stream>>>(xb, Wkv1T, bkv1, kv1b, nullptr, nullptr, nullptr, 512, 1024);
    // kv = kv1 @ Wkv2 + bkv2 -> k(rope)->krb, v->vbb
    gemm_bt<MODE_KV><<<dim3(32, 16), 256, 0, stream>>>(kv1b, Wkv2T, bkv2, krb, vbb, cosT, sinT, 2048, 512);
    vtrans<<<dim3(32, 32), 256, 0, stream>>>(vbb, vtb);
    attn_fa<<<dim3(16, 32), 256, 0, stream>>>(qrb, krb, vtb, attnf);
    // out = attn @ Wo + bo (fp32)
    gemm_bt<MODE_F32><<<dim3(32, 8), 256, 0, stream>>>(attnf, WoT, bo, out, nullptr, nullptr, nullptr, 1024, 1024);
}

// Round 2
// 275.530 us; speedup vs baseline: 1.3691x; 1.3691x over previous
//
#include <hip/hip_runtime.h>
#include <hip/hip_bf16.h>
#include <stdint.h>
#include <math.h>

#define S_ 2048
#define H_ 16
#define B_ 2

typedef __attribute__((ext_vector_type(4))) float f32x4;
typedef __attribute__((ext_vector_type(8))) short s16x8;

static __device__ __forceinline__ uint16_t f2bf(float f) {
    union { float f; uint32_t u; } x; x.f = f;
    uint32_t u = x.u;
    return (uint16_t)((u + 0x7FFFu + ((u >> 16) & 1u)) >> 16);
}

static __device__ __forceinline__ void gl_lds16(const uint16_t* g, uint16_t* l) {
    __builtin_amdgcn_global_load_lds(
        (const __attribute__((address_space(1))) unsigned int*)g,
        (__attribute__((address_space(3))) unsigned int*)l, 16, 0, 0);
}

// ---------------- prep kernels ----------------

__global__ void cvt_f32_bf16(const float* __restrict__ in, uint16_t* __restrict__ out, int n4) {
    int i = blockIdx.x * blockDim.x + threadIdx.x;
    if (i >= n4) return;
    float4 v = ((const float4*)in)[i];
    union { uint16_t h[4]; uint64_t q; } pk;
    pk.h[0] = f2bf(v.x); pk.h[1] = f2bf(v.y); pk.h[2] = f2bf(v.z); pk.h[3] = f2bf(v.w);
    ((uint64_t*)out)[i] = pk.q;
}

// in: R x C fp32 row-major  ->  out: C x R bf16 row-major
__global__ void transpose_w(const float* __restrict__ in, uint16_t* __restrict__ out, int R, int C) {
    __shared__ float sm[32][33];
    int r0 = blockIdx.x * 32, c0 = blockIdx.y * 32;
    int t = threadIdx.x;
    int rr = t >> 3, cc = (t & 7) * 4;
    float4 v = *(const float4*)(in + (size_t)(r0 + rr) * C + c0 + cc);
    sm[rr][cc] = v.x; sm[rr][cc + 1] = v.y; sm[rr][cc + 2] = v.z; sm[rr][cc + 3] = v.w;
    __syncthreads();
    union { uint16_t h[4]; uint64_t q; } pk;
    #pragma unroll
    for (int i = 0; i < 4; i++) pk.h[i] = f2bf(sm[cc + i][rr]);
    *(uint64_t*)(out + (size_t)(c0 + rr) * R + r0 + cc) = pk.q;
}

__global__ void rope_table(float* __restrict__ cosT, float* __restrict__ sinT) {
    int i = blockIdx.x * blockDim.x + threadIdx.x; // 2048*32
    int s = i >> 5, j = i & 31;
    float theta = powf(10000.0f, -2.0f * (float)j / 64.0f);
    float ang = (float)s * theta;
    cosT[i] = cosf(ang);
    sinT[i] = sinf(ang);
}

// vb: (bh, s, d=64)  ->  vt: (bh, d=64, s)
__global__ void vtrans(const uint16_t* __restrict__ vb, uint16_t* __restrict__ vt) {
    __shared__ __align__(16) uint16_t sm[64][72];
    int s0 = blockIdx.x * 64;
    int bh = blockIdx.y;
    const uint16_t* src = vb + (size_t)bh * S_ * 64;
    uint16_t* dst = vt + (size_t)bh * 64 * S_;
    int t = threadIdx.x;
    #pragma unroll
    for (int p = 0; p < 2; p++) {
        int off = p * 2048 + t * 8;
        int sl = off >> 6, d = off & 63;
        s16x8 v = *(const s16x8*)(src + (size_t)(s0 + sl) * 64 + d);
        #pragma unroll
        for (int i = 0; i < 8; i++) sm[sl][d + i] = (uint16_t)v[i];
    }
    __syncthreads();
    #pragma unroll
    for (int p = 0; p < 2; p++) {
        int off = p * 2048 + t * 8;
        int d = off >> 6, sl = off & 63;
        union { uint16_t h[8]; s16x8 v; } pk;
        #pragma unroll
        for (int i = 0; i < 8; i++) pk.h[i] = sm[sl + i][d];
        *(s16x8*)(dst + (size_t)d * S_ + s0 + sl) = pk.v;
    }
}

// ---------------- GEMM: C = A(bf16 MxK) @ BT(bf16 NxK)^T + bias ----------------

#define MODE_F32   0
#define MODE_BF16  1
#define MODE_QROPE 2
#define MODE_KV    3

// fold 1/sqrt(64) * log2(e) into Q so attention scores are in exp2 units
#define QSCALE 0.180336880f

template<int MODE>
__global__ __launch_bounds__(256, 2)
void gemm_bt(const uint16_t* __restrict__ A, const uint16_t* __restrict__ BT,
             const float* __restrict__ bias,
             void* __restrict__ out0, uint16_t* __restrict__ out2,
             const float* __restrict__ cosT, const float* __restrict__ sinT,
             int N, int K)
{
    __shared__ __align__(16) uint16_t smA[128 * 32];
    __shared__ __align__(16) uint16_t smB[128 * 32];
    const int t = threadIdx.x;
    const int l = t & 63;
    const int wid = t >> 6;
    const int wr = wid >> 1, wc = wid & 1;
    const int m0 = blockIdx.x * 128, n0 = blockIdx.y * 128;

    f32x4 acc[4][4];
    #pragma unroll
    for (int i = 0; i < 4; i++)
        #pragma unroll
        for (int j = 0; j < 4; j++) acc[i][j] = (f32x4)(0.0f);

    const int srow = t >> 2;                       // staged row
    const int ssw = (((t & 3) ^ (srow & 3)) * 8);  // inverse-swizzled source chunk
    const uint16_t* aG = A + (size_t)(m0 + srow) * K + ssw;
    const uint16_t* bG = BT + (size_t)(n0 + srow) * K + ssw;
    uint16_t* lA = smA + t * 8;
    uint16_t* lB = smB + t * 8;

    // swizzled fragment read offset: chunk = (l>>4) ^ (row&3), row&3 == l&3
    const int rchunk = (((l >> 4) ^ (l & 3)) * 8);

    for (int k0 = 0; k0 < K; k0 += 32) {
        __syncthreads();
        gl_lds16(aG + k0, lA);
        gl_lds16(aG + (size_t)64 * K + k0, lA + 2048);
        gl_lds16(bG + k0, lB);
        gl_lds16(bG + (size_t)64 * K + k0, lB + 2048);
        __syncthreads();
        s16x8 af[4], bfr[4];
        #pragma unroll
        for (int mf = 0; mf < 4; mf++)
            af[mf] = *(const s16x8*)(smA + (wr * 64 + mf * 16 + (l & 15)) * 32 + rchunk);
        #pragma unroll
        for (int nf = 0; nf < 4; nf++)
            bfr[nf] = *(const s16x8*)(smB + (wc * 64 + nf * 16 + (l & 15)) * 32 + rchunk);
        #pragma unroll
        for (int mf = 0; mf < 4; mf++)
            #pragma unroll
            for (int nf = 0; nf < 4; nf++)
                acc[mf][nf] = __builtin_amdgcn_mfma_f32_16x16x32_bf16(af[mf], bfr[nf], acc[mf][nf], 0, 0, 0);
    }

    const int rbase = m0 + wr * 64 + ((l >> 4) << 2);
    const int cbase = n0 + wc * 64 + (l & 15);
    #pragma unroll
    for (int mf = 0; mf < 4; mf++) {
        #pragma unroll
        for (int nf = 0; nf < 4; nf++) {
            const int col = cbase + nf * 16;
            const float bv = bias[col];
            #pragma unroll
            for (int r = 0; r < 4; r++) {
                const int row = rbase + mf * 16 + r;
                float v = acc[mf][nf][r] + bv;
                if constexpr (MODE == MODE_F32) {
                    ((float*)out0)[(size_t)row * N + col] = v;
                } else if constexpr (MODE == MODE_BF16) {
                    ((uint16_t*)out0)[(size_t)row * N + col] = f2bf(v);
                } else {
                    float other = __shfl_xor(v, 1);
                    int s = row & (S_ - 1);
                    int b = row >> 11;
                    if constexpr (MODE == MODE_QROPE) {
                        int h = col >> 6, d = col & 63;
                        float c = cosT[s * 32 + (d >> 1)];
                        float sn = sinT[s * 32 + (d >> 1)];
                        float o = (d & 1) ? (other * sn + v * c) : (v * c - other * sn);
                        o *= QSCALE;
                        ((uint16_t*)out0)[((size_t)(b * H_ + h) * S_ + s) * 64 + d] = f2bf(o);
                    } else { // MODE_KV
                        if (col < 1024) {
                            int h = col >> 6, d = col & 63;
                            float c = cosT[s * 32 + (d >> 1)];
                            float sn = sinT[s * 32 + (d >> 1)];
                            float o = (d & 1) ? (other * sn + v * c) : (v * c - other * sn);
                            ((uint16_t*)out0)[((size_t)(b * H_ + h) * S_ + s) * 64 + d] = f2bf(o);
                        } else {
                            int cc = col - 1024;
                            int h = cc >> 6, d = cc & 63;
                            out2[((size_t)(b * H_ + h) * S_ + s) * 64 + d] = f2bf(v);
                        }
                    }
                }
            }
        }
    }
}

// ---------------- causal flash attention ----------------
// qr (pre-scaled by QSCALE), kr: (bh, s, 64) bf16; vt: (bh, 64, s) bf16
// attnf: (b, s, h*64) bf16
// Block = 4 waves, wave w owns 16 q-rows of a 64-row q-tile.
// Pairing: block x=j processes q-tiles j and 31-j -> constant 33 k-tiles/block.
// LDS tiles chunk-swizzled: 16B chunk c of row r stored at chunk c^(r&7).

__global__ __launch_bounds__(256, 4)
void attn_fa(const uint16_t* __restrict__ qr, const uint16_t* __restrict__ kr,
             const uint16_t* __restrict__ vt, uint16_t* __restrict__ attnf)
{
    __shared__ __align__(16) uint16_t smK[2][4096];
    __shared__ __align__(16) uint16_t smV[2][4096];
    __shared__ __align__(16) uint16_t smP[4096];

    const int t = threadIdx.x;
    const int l = t & 63;
    const int w = t >> 6;
    const int bh = blockIdx.y;
    const int bb = bh >> 4, hh = bh & 15;
    const uint16_t* qB = qr + (size_t)bh * S_ * 64;
    const uint16_t* kB = kr + (size_t)bh * S_ * 64;
    const uint16_t* vB = vt + (size_t)bh * 64 * S_;

    const int arow = t >> 3;                         // staged row (0..31)
    const int asw = (((t & 7) ^ (arow & 7)) * 8);    // inverse-swizzled source chunk
    const int frow = l & 15;
    const int fg = l >> 4;
    const int rsw = l & 7;                           // read swizzle key (row&7 of frag rows)

    auto stage = [&](int buf, int kv0) {
        gl_lds16(kB + (size_t)(kv0 + arow) * 64 + asw, &smK[buf][t * 8]);
        gl_lds16(kB + (size_t)(kv0 + arow + 32) * 64 + asw, &smK[buf][2048 + t * 8]);
        gl_lds16(vB + (size_t)arow * S_ + kv0 + asw, &smV[buf][t * 8]);
        gl_lds16(vB + (size_t)(arow + 32) * S_ + kv0 + asw, &smV[buf][2048 + t * 8]);
    };

    auto process = [&](int qt) {
        s16x8 qf[2];
        {
            const uint16_t* qp = qB + (size_t)(qt * 64 + w * 16 + frow) * 64 + fg * 8;
            qf[0] = *(const s16x8*)qp;
            qf[1] = *(const s16x8*)(qp + 32);
        }
        float mrow[4], lrow[4];
        f32x4 oacc[4];
        #pragma unroll
        for (int r = 0; r < 4; r++) { mrow[r] = -INFINITY; lrow[r] = 0.0f; }
        #pragma unroll
        for (int nf = 0; nf < 4; nf++) oacc[nf] = (f32x4)(0.0f);

        const int nkt = qt + 1;
        int cur = 0;
        stage(0, qt ? 0 : 0);
        // (first tile kv0 = 0 always)
        __syncthreads();

        for (int kt = 0; kt < nkt; kt++) {
            if (kt + 1 < nkt) stage(cur ^ 1, (kt + 1) * 64);

            // ---- S = Q K^T (exp2 units, QSCALE folded into Q) ----
            f32x4 sacc[4];
            #pragma unroll
            for (int nf = 0; nf < 4; nf++) sacc[nf] = (f32x4)(0.0f);
            #pragma unroll
            for (int kk = 0; kk < 2; kk++) {
                #pragma unroll
                for (int nf = 0; nf < 4; nf++) {
                    s16x8 kf = *(const s16x8*)(&smK[cur][(nf * 16 + frow) * 64 + (((kk * 4 + fg) ^ rsw) * 8)]);
                    sacc[nf] = __builtin_amdgcn_mfma_f32_16x16x32_bf16(qf[kk], kf, sacc[nf], 0, 0, 0);
                }
            }

            // ---- online softmax ----
            const bool diag = (kt == qt);
            #pragma unroll
            for (int r = 0; r < 4; r++) {
                const int qloc = w * 16 + fg * 4 + r;
                float sv[4];
                #pragma unroll
                for (int nf = 0; nf < 4; nf++) {
                    float s = sacc[nf][r];
                    if (diag) s = (nf * 16 + frow <= qloc) ? s : -INFINITY;
                    sv[nf] = s;
                }
                float mx = fmaxf(fmaxf(sv[0], sv[1]), fmaxf(sv[2], sv[3]));
                mx = fmaxf(mx, __shfl_xor(mx, 1));
                mx = fmaxf(mx, __shfl_xor(mx, 2));
                mx = fmaxf(mx, __shfl_xor(mx, 4));
                mx = fmaxf(mx, __shfl_xor(mx, 8));
                float nm = fmaxf(mrow[r], mx);
                float fac = __builtin_amdgcn_exp2f(mrow[r] - nm);
                float ps = 0.0f;
                float pb[4];
                #pragma unroll
                for (int nf = 0; nf < 4; nf++) {
                    float p = __builtin_amdgcn_exp2f(sv[nf] - nm);
                    pb[nf] = p;
                    ps += p;
                }
                ps += __shfl_xor(ps, 1);
                ps += __shfl_xor(ps, 2);
                ps += __shfl_xor(ps, 4);
                ps += __shfl_xor(ps, 8);
                lrow[r] = lrow[r] * fac + ps;
                mrow[r] = nm;
                #pragma unroll
                for (int nf = 0; nf < 4; nf++) oacc[nf][r] *= fac;
                const int prow = w * 16 + fg * 4 + r;
                const int prm = (fg * 4 + r) & 7;
                #pragma unroll
                for (int nf = 0; nf < 4; nf++)
                    smP[prow * 64 + (((nf * 2 + (frow >> 3)) ^ prm) * 8) + (frow & 7)] = f2bf(pb[nf]);
            }

            // ---- O += P V ---- (P rows are wave-private: no barrier needed)
            #pragma unroll
            for (int kk = 0; kk < 2; kk++) {
                s16x8 pf = *(const s16x8*)(&smP[(w * 16 + frow) * 64 + (((kk * 4 + fg) ^ rsw) * 8)]);
                #pragma unroll
                for (int nf = 0; nf < 4; nf++) {
                    s16x8 vf = *(const s16x8*)(&smV[cur][(nf * 16 + frow) * 64 + (((kk * 4 + fg) ^ rsw) * 8)]);
                    oacc[nf] = __builtin_amdgcn_mfma_f32_16x16x32_bf16(pf, vf, oacc[nf], 0, 0, 0);
                }
            }

            __syncthreads();
            cur ^= 1;
        }

        // ---- epilogue ----
        #pragma unroll
        for (int r = 0; r < 4; r++) {
            float rinv = __builtin_amdgcn_rcpf(lrow[r]);
            const int qrow = qt * 64 + w * 16 + fg * 4 + r;
            #pragma unroll
            for (int nf = 0; nf < 4; nf++) {
                int d = nf * 16 + frow;
                attnf[((size_t)(bb * S_ + qrow)) * 1024 + hh * 64 + d] = f2bf(oacc[nf][r] * rinv);
            }
        }
    };

    const int j = blockIdx.x;
    process(j);
    process(31 - j);
}

// ---------------- launch ----------------

extern "C" void kernel_launch(void* const* d_in, const int* in_sizes, int n_in,
                              void* d_out, int out_size, void* d_ws, size_t ws_size,
                              hipStream_t stream)
{
    const float* x    = (const float*)d_in[0];
    const float* Wq   = (const float*)d_in[1];
    const float* bq   = (const float*)d_in[2];
    const float* Wkv1 = (const float*)d_in[3];
    const float* bkv1 = (const float*)d_in[4];
    const float* Wkv2 = (const float*)d_in[5];
    const float* bkv2 = (const float*)d_in[6];
    const float* Wo   = (const float*)d_in[7];
    const float* bo   = (const float*)d_in[8];
    float* out = (float*)d_out;
    char* ws = (char*)d_ws;

    uint16_t* xb    = (uint16_t*)(ws + 0);            // 4096x1024 bf16   8 MB
    uint16_t* WqT   = (uint16_t*)(ws + 8388608);      // 1024x1024        2 MB
    uint16_t* Wkv1T = (uint16_t*)(ws + 10485760);     // 512x1024         1 MB
    uint16_t* Wkv2T = (uint16_t*)(ws + 11534336);     // 2048x512         2 MB
    uint16_t* WoT   = (uint16_t*)(ws + 13631488);     // 1024x1024        2 MB
    float*    cosT  = (float*)(ws + 15728640);        // 2048x32 f32      256 KB
    float*    sinT  = (float*)(ws + 15990784);        // 256 KB
    uint16_t* qrb   = (uint16_t*)(ws + 16252928);     // (bh,s,d)         8 MB
    uint16_t* kv1b  = (uint16_t*)(ws + 24641536);     // 4096x512         4 MB
    uint16_t* krb   = (uint16_t*)(ws + 28835840);     // (bh,s,d)         8 MB
    uint16_t* vbb   = (uint16_t*)(ws + 37224448);     // (bh,s,d)         8 MB
    uint16_t* vtb   = (uint16_t*)(ws + 45613056);     // (bh,d,s)         8 MB
    uint16_t* attnf = (uint16_t*)(ws + 54001664);     // 4096x1024        8 MB

    cvt_f32_bf16<<<4096, 256, 0, stream>>>(x, xb, 1048576);
    transpose_w<<<dim3(32, 32), 256, 0, stream>>>(Wq, WqT, 1024, 1024);
    transpose_w<<<dim3(32, 16), 256, 0, stream>>>(Wkv1, Wkv1T, 1024, 512);
    transpose_w<<<dim3(16, 64), 256, 0, stream>>>(Wkv2, Wkv2T, 512, 2048);
    transpose_w<<<dim3(32, 32), 256, 0, stream>>>(Wo, WoT, 1024, 1024);
    rope_table<<<256, 256, 0, stream>>>(cosT, sinT);

    // q = x @ Wq + bq, rope, *QSCALE -> qrb (bh,s,d)
    gemm_bt<MODE_QROPE><<<dim3(32, 8), 256, 0, stream>>>(xb, WqT, bq, qrb, nullptr, cosT, sinT, 1024, 1024);
    // kv1 = x @ Wkv1 + bkv1 -> bf16 row-major
    gemm_bt<MODE_BF16><<<dim3(32, 4), 256, 0, stream>>>(xb, Wkv1T, bkv1, kv1b, nullptr, nullptr, nullptr, 512, 1024);
    // kv = kv1 @ Wkv2 + bkv2 -> k(rope)->krb, v->vbb
    gemm_bt<MODE_KV><<<dim3(32, 16), 256, 0, stream>>>(kv1b, Wkv2T, bkv2, krb, vbb, cosT, sinT, 2048, 512);
    vtrans<<<dim3(32, 32), 256, 0, stream>>>(vbb, vtb);
    attn_fa<<<dim3(16, 32), 256, 0, stream>>>(qrb, krb, vtb, attnf);
    // out = attn @ Wo + bo (fp32)
    gemm_bt<MODE_F32><<<dim3(32, 8), 256, 0, stream>>>(attnf, WoT, bo, out, nullptr, nullptr, nullptr, 1024, 1024);
}

// Round 3
// 247.194 us; speedup vs baseline: 1.5261x; 1.1146x over previous
//
#include <hip/hip_runtime.h>
#include <hip/hip_bf16.h>
#include <stdint.h>
#include <math.h>

#define S_ 2048
#define H_ 16
#define B_ 2

typedef __attribute__((ext_vector_type(4))) float f32x4;
typedef __attribute__((ext_vector_type(8))) short s16x8;

static __device__ __forceinline__ uint16_t f2bf(float f) {
    union { float f; uint32_t u; } x; x.f = f;
    uint32_t u = x.u;
    return (uint16_t)((u + 0x7FFFu + ((u >> 16) & 1u)) >> 16);
}

// packed f32x2 -> bf16x2 (RNE), low half = a
static __device__ __forceinline__ uint32_t cvtpk_bf16(float a, float b) {
    uint32_t d;
    asm("v_cvt_pk_bf16_f32 %0, %1, %2" : "=v"(d) : "v"(a), "v"(b));
    return d;
}

static __device__ __forceinline__ void gl_lds16(const uint16_t* g, uint16_t* l) {
    __builtin_amdgcn_global_load_lds(
        (const __attribute__((address_space(1))) unsigned int*)g,
        (__attribute__((address_space(3))) unsigned int*)l, 16, 0, 0);
}

// ---------------- prep kernels ----------------

__global__ void cvt_f32_bf16(const float* __restrict__ in, uint16_t* __restrict__ out, int n4) {
    int i = blockIdx.x * blockDim.x + threadIdx.x;
    if (i >= n4) return;
    float4 v = ((const float4*)in)[i];
    union { uint16_t h[4]; uint64_t q; } pk;
    pk.h[0] = f2bf(v.x); pk.h[1] = f2bf(v.y); pk.h[2] = f2bf(v.z); pk.h[3] = f2bf(v.w);
    ((uint64_t*)out)[i] = pk.q;
}

// in: R x C fp32 row-major  ->  out: C x R bf16 row-major
__global__ void transpose_w(const float* __restrict__ in, uint16_t* __restrict__ out, int R, int C) {
    __shared__ float sm[32][33];
    int r0 = blockIdx.x * 32, c0 = blockIdx.y * 32;
    int t = threadIdx.x;
    int rr = t >> 3, cc = (t & 7) * 4;
    float4 v = *(const float4*)(in + (size_t)(r0 + rr) * C + c0 + cc);
    sm[rr][cc] = v.x; sm[rr][cc + 1] = v.y; sm[rr][cc + 2] = v.z; sm[rr][cc + 3] = v.w;
    __syncthreads();
    union { uint16_t h[4]; uint64_t q; } pk;
    #pragma unroll
    for (int i = 0; i < 4; i++) pk.h[i] = f2bf(sm[cc + i][rr]);
    *(uint64_t*)(out + (size_t)(c0 + rr) * R + r0 + cc) = pk.q;
}

__global__ void rope_table(float* __restrict__ cosT, float* __restrict__ sinT) {
    int i = blockIdx.x * blockDim.x + threadIdx.x; // 2048*32
    int s = i >> 5, j = i & 31;
    float theta = exp2f(-0.41524101f * (float)j);  // 10000^(-2j/64)
    float ang = (float)s * theta;
    cosT[i] = cosf(ang);
    sinT[i] = sinf(ang);
}

// vb: (bh, s, d=64)  ->  vt: (bh, d=64, s)
__global__ void vtrans(const uint16_t* __restrict__ vb, uint16_t* __restrict__ vt) {
    __shared__ __align__(16) uint16_t sm[64][72];
    int s0 = blockIdx.x * 64;
    int bh = blockIdx.y;
    const uint16_t* src = vb + (size_t)bh * S_ * 64;
    uint16_t* dst = vt + (size_t)bh * 64 * S_;
    int t = threadIdx.x;
    #pragma unroll
    for (int p = 0; p < 2; p++) {
        int off = p * 2048 + t * 8;
        int sl = off >> 6, d = off & 63;
        s16x8 v = *(const s16x8*)(src + (size_t)(s0 + sl) * 64 + d);
        #pragma unroll
        for (int i = 0; i < 8; i++) sm[sl][d + i] = (uint16_t)v[i];
    }
    __syncthreads();
    #pragma unroll
    for (int p = 0; p < 2; p++) {
        int off = p * 2048 + t * 8;
        int d = off >> 6, sl = off & 63;
        union { uint16_t h[8]; s16x8 v; } pk;
        #pragma unroll
        for (int i = 0; i < 8; i++) pk.h[i] = sm[sl + i][d];
        *(s16x8*)(dst + (size_t)d * S_ + s0 + sl) = pk.v;
    }
}

// ---------------- GEMM: C = A(bf16 MxK) @ BT(bf16 NxK)^T + bias ----------------
// 128x64 tile, BK=32, 4 waves (2x2: wave = 64x32), double-buffered T3-min prefetch.

#define MODE_F32   0
#define MODE_BF16  1
#define MODE_QROPE 2
#define MODE_KV    3

// fold 1/sqrt(64) * log2(e) into Q so attention scores are in exp2 units
#define QSCALE 0.180336880f

template<int MODE>
__global__ __launch_bounds__(256, 4)
void gemm_bt(const uint16_t* __restrict__ A, const uint16_t* __restrict__ BT,
             const float* __restrict__ bias,
             void* __restrict__ out0, uint16_t* __restrict__ out2,
             const float* __restrict__ cosT, const float* __restrict__ sinT,
             int N, int K)
{
    __shared__ __align__(16) uint16_t smA[2][4096];  // 128x32
    __shared__ __align__(16) uint16_t smB[2][2048];  // 64x32
    const int t = threadIdx.x;
    const int l = t & 63;
    const int wid = t >> 6;
    const int wr = wid >> 1, wc = wid & 1;
    const int m0 = blockIdx.x * 128, n0 = blockIdx.y * 64;

    f32x4 acc[4][2];
    #pragma unroll
    for (int i = 0; i < 4; i++)
        #pragma unroll
        for (int j = 0; j < 2; j++) acc[i][j] = (f32x4)(0.0f);

    const int srow = t >> 2;                       // staged row (0..63)
    const int ssw = (((t & 3) ^ (srow & 3)) * 8);  // inverse-swizzled source chunk
    const uint16_t* aG = A + (size_t)(m0 + srow) * K + ssw;
    const uint16_t* bG = BT + (size_t)(n0 + srow) * K + ssw;

    // swizzled fragment read offset: chunk = (l>>4) ^ (row&3), row&3 == l&3
    const int rchunk = (((l >> 4) ^ (l & 3)) * 8);

    auto stage = [&](int buf, int k0) {
        gl_lds16(aG + k0, &smA[buf][t * 8]);
        gl_lds16(aG + (size_t)64 * K + k0, &smA[buf][2048 + t * 8]);
        gl_lds16(bG + k0, &smB[buf][t * 8]);
    };

    stage(0, 0);
    __syncthreads();
    int cur = 0;
    for (int k0 = 0; k0 < K; k0 += 32) {
        if (k0 + 32 < K) stage(cur ^ 1, k0 + 32);
        s16x8 af[4], bfr[2];
        #pragma unroll
        for (int mf = 0; mf < 4; mf++)
            af[mf] = *(const s16x8*)(&smA[cur][(wr * 64 + mf * 16 + (l & 15)) * 32 + rchunk]);
        #pragma unroll
        for (int nf = 0; nf < 2; nf++)
            bfr[nf] = *(const s16x8*)(&smB[cur][(wc * 32 + nf * 16 + (l & 15)) * 32 + rchunk]);
        #pragma unroll
        for (int mf = 0; mf < 4; mf++)
            #pragma unroll
            for (int nf = 0; nf < 2; nf++)
                acc[mf][nf] = __builtin_amdgcn_mfma_f32_16x16x32_bf16(af[mf], bfr[nf], acc[mf][nf], 0, 0, 0);
        __syncthreads();
        cur ^= 1;
    }

    const int rbase = m0 + wr * 64 + ((l >> 4) << 2);
    const int cbase = n0 + wc * 32 + (l & 15);
    #pragma unroll
    for (int mf = 0; mf < 4; mf++) {
        #pragma unroll
        for (int nf = 0; nf < 2; nf++) {
            const int col = cbase + nf * 16;
            const float bv = bias[col];
            #pragma unroll
            for (int r = 0; r < 4; r++) {
                const int row = rbase + mf * 16 + r;
                float v = acc[mf][nf][r] + bv;
                if constexpr (MODE == MODE_F32) {
                    ((float*)out0)[(size_t)row * N + col] = v;
                } else if constexpr (MODE == MODE_BF16) {
                    ((uint16_t*)out0)[(size_t)row * N + col] = f2bf(v);
                } else {
                    float other = __shfl_xor(v, 1);
                    int s = row & (S_ - 1);
                    int b = row >> 11;
                    if constexpr (MODE == MODE_QROPE) {
                        int h = col >> 6, d = col & 63;
                        float c = cosT[s * 32 + (d >> 1)];
                        float sn = sinT[s * 32 + (d >> 1)];
                        float o = (d & 1) ? (other * sn + v * c) : (v * c - other * sn);
                        o *= QSCALE;
                        ((uint16_t*)out0)[((size_t)(b * H_ + h) * S_ + s) * 64 + d] = f2bf(o);
                    } else { // MODE_KV
                        if (col < 1024) {
                            int h = col >> 6, d = col & 63;
                            float c = cosT[s * 32 + (d >> 1)];
                            float sn = sinT[s * 32 + (d >> 1)];
                            float o = (d & 1) ? (other * sn + v * c) : (v * c - other * sn);
                            ((uint16_t*)out0)[((size_t)(b * H_ + h) * S_ + s) * 64 + d] = f2bf(o);
                        } else {
                            int cc = col - 1024;
                            int h = cc >> 6, d = cc & 63;
                            out2[((size_t)(b * H_ + h) * S_ + s) * 64 + d] = f2bf(v);
                        }
                    }
                }
            }
        }
    }
}

// ---------------- causal flash attention (swapped-operand, in-register softmax) ----
// qr (pre-scaled by QSCALE), kr: (bh, s, 64) bf16; vt: (bh, 64, s) bf16
// attnf: (b, s, h*64) bf16
// 4 waves/block; wave w owns q-rows [qt*64 + w*16, +16). Grid (32,32): qt = 31-bx (big first).
// S^T = mfma(K_frag, Q_frag): lane holds S[q=l&15][k = nf*16 + fg*4 + r] -> row stats
// are 15 in-reg ops + 2 shuffles. P packed via v_cvt_pk_bf16_f32, 4x ds_write_b64.

__global__ __launch_bounds__(256, 4)
void attn_fa(const uint16_t* __restrict__ qr, const uint16_t* __restrict__ kr,
             const uint16_t* __restrict__ vt, uint16_t* __restrict__ attnf)
{
    __shared__ __align__(16) uint16_t smK[2][4096];
    __shared__ __align__(16) uint16_t smV[2][4096];
    __shared__ __align__(16) uint16_t smP[4096];     // per-wave 16x64 regions

    const int t = threadIdx.x;
    const int l = t & 63;
    const int w = t >> 6;
    const int bh = blockIdx.y;
    const int bb = bh >> 4, hh = bh & 15;
    const uint16_t* qB = qr + (size_t)bh * S_ * 64;
    const uint16_t* kB = kr + (size_t)bh * S_ * 64;
    const uint16_t* vB = vt + (size_t)bh * 64 * S_;

    const int arow = t >> 3;                         // staged row (0..31)
    const int asw = (((t & 7) ^ (arow & 7)) * 8);    // inverse-swizzled source chunk
    const int frow = l & 15;
    const int fg = l >> 4;
    const int rsw = frow & 7;                        // read swizzle key

    const int qt = 31 - blockIdx.x;
    const int qglob = qt * 64 + w * 16 + frow;

    auto stage = [&](int buf, int kv0) {
        gl_lds16(kB + (size_t)(kv0 + arow) * 64 + asw, &smK[buf][t * 8]);
        gl_lds16(kB + (size_t)(kv0 + arow + 32) * 64 + asw, &smK[buf][2048 + t * 8]);
        gl_lds16(vB + (size_t)arow * S_ + kv0 + asw, &smV[buf][t * 8]);
        gl_lds16(vB + (size_t)(arow + 32) * S_ + kv0 + asw, &smV[buf][2048 + t * 8]);
    };

    // Q fragments (B-operand layout == A-frag of Q): lane holds Q[qglob][kk*32+fg*8..+7]
    s16x8 qf[2];
    {
        const uint16_t* qp = qB + (size_t)qglob * 64 + fg * 8;
        qf[0] = *(const s16x8*)qp;
        qf[1] = *(const s16x8*)(qp + 32);
    }

    float mreg = -INFINITY, lsum = 0.0f;
    f32x4 oacc[4];
    #pragma unroll
    for (int nf = 0; nf < 4; nf++) oacc[nf] = (f32x4)(0.0f);

    stage(0, 0);
    __syncthreads();
    int cur = 0;
    const int wfr = w * 16 + frow;     // causal rhs within diag tile

    for (int kt = 0; kt <= qt; kt++) {
        if (kt < qt) stage(cur ^ 1, (kt + 1) * 64);

        // ---- S^T = K Q^T (exp2 units; QSCALE folded into Q) ----
        f32x4 sacc[4];
        #pragma unroll
        for (int nf = 0; nf < 4; nf++) sacc[nf] = (f32x4)(0.0f);
        #pragma unroll
        for (int kk = 0; kk < 2; kk++) {
            #pragma unroll
            for (int nf = 0; nf < 4; nf++) {
                s16x8 kf = *(const s16x8*)(&smK[cur][(nf * 16 + frow) * 64 + (((kk * 4 + fg) ^ rsw) * 8)]);
                sacc[nf] = __builtin_amdgcn_mfma_f32_16x16x32_bf16(kf, qf[kk], sacc[nf], 0, 0, 0);
            }
        }

        // ---- in-register online softmax (lane owns one q-row) ----
        if (kt == qt) {
            #pragma unroll
            for (int nf = 0; nf < 4; nf++)
                #pragma unroll
                for (int r = 0; r < 4; r++)
                    sacc[nf][r] = (nf * 16 + fg * 4 + r <= wfr) ? sacc[nf][r] : -INFINITY;
        }
        float mx = -INFINITY;
        #pragma unroll
        for (int nf = 0; nf < 4; nf++)
            #pragma unroll
            for (int r = 0; r < 4; r++) mx = fmaxf(mx, sacc[nf][r]);
        mx = fmaxf(mx, __shfl_xor(mx, 16));
        mx = fmaxf(mx, __shfl_xor(mx, 32));
        float nm = fmaxf(mreg, mx);
        float fac = __builtin_amdgcn_exp2f(mreg - nm);
        mreg = nm;
        float ps = 0.0f;
        #pragma unroll
        for (int nf = 0; nf < 4; nf++)
            #pragma unroll
            for (int r = 0; r < 4; r++) {
                float p = __builtin_amdgcn_exp2f(sacc[nf][r] - nm);
                sacc[nf][r] = p;
                ps += p;
            }
        ps += __shfl_xor(ps, 16);
        ps += __shfl_xor(ps, 32);
        lsum = lsum * fac + ps;

        // ---- pack P to bf16 and store (4 x ds_write_b64, swizzled) ----
        #pragma unroll
        for (int nf = 0; nf < 4; nf++) {
            uint32_t w0 = cvtpk_bf16(sacc[nf][0], sacc[nf][1]);
            uint32_t w1 = cvtpk_bf16(sacc[nf][2], sacc[nf][3]);
            int chunk = (nf * 2 + (fg >> 1)) ^ rsw;
            uint2 pkd; pkd.x = w0; pkd.y = w1;
            *(uint2*)(&smP[(w * 16 + frow) * 64 + chunk * 8 + (fg & 1) * 4]) = pkd;
        }

        // ---- O rescale (fac redistributed: oacc row q_local = fg*4+r) ----
        #pragma unroll
        for (int r = 0; r < 4; r++) {
            float facr = __shfl(fac, fg * 16 + fg * 4 + r);
            #pragma unroll
            for (int nf = 0; nf < 4; nf++) oacc[nf][r] *= facr;
        }

        // ---- O += P V (P wave-private in LDS) ----
        #pragma unroll
        for (int kk = 0; kk < 2; kk++) {
            s16x8 pf = *(const s16x8*)(&smP[(w * 16 + frow) * 64 + (((kk * 4 + fg) ^ rsw) * 8)]);
            #pragma unroll
            for (int nf = 0; nf < 4; nf++) {
                s16x8 vf = *(const s16x8*)(&smV[cur][(nf * 16 + frow) * 64 + (((kk * 4 + fg) ^ rsw) * 8)]);
                oacc[nf] = __builtin_amdgcn_mfma_f32_16x16x32_bf16(pf, vf, oacc[nf], 0, 0, 0);
            }
        }

        __syncthreads();
        cur ^= 1;
    }

    // ---- epilogue ----
    #pragma unroll
    for (int r = 0; r < 4; r++) {
        float lr = __shfl(lsum, fg * 16 + fg * 4 + r);
        float rinv = __builtin_amdgcn_rcpf(lr);
        const int qrow = qt * 64 + w * 16 + fg * 4 + r;
        #pragma unroll
        for (int nf = 0; nf < 4; nf++) {
            int d = nf * 16 + frow;
            attnf[((size_t)(bb * S_ + qrow)) * 1024 + hh * 64 + d] = f2bf(oacc[nf][r] * rinv);
        }
    }
}

// ---------------- launch ----------------

extern "C" void kernel_launch(void* const* d_in, const int* in_sizes, int n_in,
                              void* d_out, int out_size, void* d_ws, size_t ws_size,
                              hipStream_t stream)
{
    const float* x    = (const float*)d_in[0];
    const float* Wq   = (const float*)d_in[1];
    const float* bq   = (const float*)d_in[2];
    const float* Wkv1 = (const float*)d_in[3];
    const float* bkv1 = (const float*)d_in[4];
    const float* Wkv2 = (const float*)d_in[5];
    const float* bkv2 = (const float*)d_in[6];
    const float* Wo   = (const float*)d_in[7];
    const float* bo   = (const float*)d_in[8];
    float* out = (float*)d_out;
    char* ws = (char*)d_ws;

    uint16_t* xb    = (uint16_t*)(ws + 0);            // 4096x1024 bf16   8 MB
    uint16_t* WqT   = (uint16_t*)(ws + 8388608);      // 1024x1024        2 MB
    uint16_t* Wkv1T = (uint16_t*)(ws + 10485760);     // 512x1024         1 MB
    uint16_t* Wkv2T = (uint16_t*)(ws + 11534336);     // 2048x512         2 MB
    uint16_t* WoT   = (uint16_t*)(ws + 13631488);     // 1024x1024        2 MB
    float*    cosT  = (float*)(ws + 15728640);        // 2048x32 f32      256 KB
    float*    sinT  = (float*)(ws + 15990784);        // 256 KB
    uint16_t* qrb   = (uint16_t*)(ws + 16252928);     // (bh,s,d)         8 MB
    uint16_t* kv1b  = (uint16_t*)(ws + 24641536);     // 4096x512         4 MB
    uint16_t* krb   = (uint16_t*)(ws + 28835840);     // (bh,s,d)         8 MB
    uint16_t* vbb   = (uint16_t*)(ws + 37224448);     // (bh,s,d)         8 MB
    uint16_t* vtb   = (uint16_t*)(ws + 45613056);     // (bh,d,s)         8 MB
    uint16_t* attnf = (uint16_t*)(ws + 54001664);     // 4096x1024        8 MB

    cvt_f32_bf16<<<4096, 256, 0, stream>>>(x, xb, 1048576);
    transpose_w<<<dim3(32, 32), 256, 0, stream>>>(Wq, WqT, 1024, 1024);
    transpose_w<<<dim3(32, 16), 256, 0, stream>>>(Wkv1, Wkv1T, 1024, 512);
    transpose_w<<<dim3(16, 64), 256, 0, stream>>>(Wkv2, Wkv2T, 512, 2048);
    transpose_w<<<dim3(32, 32), 256, 0, stream>>>(Wo, WoT, 1024, 1024);
    rope_table<<<256, 256, 0, stream>>>(cosT, sinT);

    // q = x @ Wq + bq, rope, *QSCALE -> qrb (bh,s,d)
    gemm_bt<MODE_QROPE><<<dim3(32, 16), 256, 0, stream>>>(xb, WqT, bq, qrb, nullptr, cosT, sinT, 1024, 1024);
    // kv1 = x @ Wkv1 + bkv1 -> bf16 row-major
    gemm_bt<MODE_BF16><<<dim3(32, 8), 256, 0, stream>>>(xb, Wkv1T, bkv1, kv1b, nullptr, nullptr, nullptr, 512, 1024);
    // kv = kv1 @ Wkv2 + bkv2 -> k(rope)->krb, v->vbb
    gemm_bt<MODE_KV><<<dim3(32, 32), 256, 0, stream>>>(kv1b, Wkv2T, bkv2, krb, vbb, cosT, sinT, 2048, 512);
    vtrans<<<dim3(32, 32), 256, 0, stream>>>(vbb, vtb);
    attn_fa<<<dim3(32, 32), 256, 0, stream>>>(qrb, krb, vtb, attnf);
    // out = attn @ Wo + bo (fp32)
    gemm_bt<MODE_F32><<<dim3(32, 16), 256, 0, stream>>>(attnf, WoT, bo, out, nullptr, nullptr, nullptr, 1024, 1024);
}